// Round 1
// baseline (512.551 us; speedup 1.0000x reference)
//
#include <hip/hip_runtime.h>

// Problem constants (fixed by setup_inputs: H=W=256, WIN=8, NCAV=2, C=256, HEADS=8)
#define NWIN 2048
#define NT   64
#define CDIM 256
#define NHEAD 8
#define HD   32
#define SCALE 0.17677669529663687f   // hd^-0.5 = 1/sqrt(32)

typedef short bfrag __attribute__((ext_vector_type(8)));   // 8 bf16 (4 VGPRs)
typedef float f4    __attribute__((ext_vector_type(4)));   // MFMA C/D
typedef unsigned short us4 __attribute__((ext_vector_type(4)));

__device__ __forceinline__ unsigned short f2bf(float f){
  unsigned u = __builtin_bit_cast(unsigned, f);
  u += 0x7FFFu + ((u >> 16) & 1u);       // round-to-nearest-even
  return (unsigned short)(u >> 16);
}

__device__ __forceinline__ f4 mfma16(bfrag a, bfrag b, f4 c){
  return __builtin_amdgcn_mfma_f32_16x16x32_bf16(a, b, c, 0, 0, 0);
}

// ---------------------------------------------------------------------------
// Prep: build bf16 W^T (q-scaled), fused bias vector, rel_bias table, ego bias
// ws layout: [0,512K) WT bf16 (1024 out_ch x 256 in_ch; rows 0-255 q*scale,
// 256-511 k, 512-767 v, 768-1023 Wp^T) | [512K,640K) rel_bias f32 [h][i][j]
// | [640K,704K) ego_bias f32 [window][head] | [704K,+3K) bqkv f32 (768)
// ---------------------------------------------------------------------------
__global__ void prep_kernel(const float* __restrict__ aff,
                            const float* __restrict__ Wq,  const float* __restrict__ bq,
                            const float* __restrict__ Wkv, const float* __restrict__ bkv,
                            const float* __restrict__ Wp,
                            const float* __restrict__ relt, const float* __restrict__ egot,
                            unsigned short* __restrict__ wt, float* __restrict__ relb,
                            float* __restrict__ egob, float* __restrict__ bqkv)
{
  const int bid = blockIdx.x, tid = threadIdx.x;
  if (bid < 1024) {                       // weight transpose + bf16
    int r = bid, c = tid;                 // r = out_ch, c = in_ch
    float v;
    if (r < 256)      v = Wq[c*256 + r] * SCALE;
    else if (r < 768) v = Wkv[c*512 + (r - 256)];   // k: cols 0..255, v: 256..511
    else              v = Wp[c*256 + (r - 768)];
    wt[r*256 + c] = f2bf(v);
  } else if (bid < 1152) {                // rel_bias: e = h*4096 + i*64 + j
    int e = (bid - 1024)*256 + tid;
    int h = e >> 12, i = (e >> 6) & 63, j = e & 63;
    int yi = i >> 3, xi = i & 7, yj = j >> 3, xj = j & 7;
    int ridx = (yi - yj + 7)*15 + (xi - xj + 7);
    relb[e] = relt[ridx*8 + h];
  } else if (bid == 1152) {               // ego bias (global max-reduce inside)
    __shared__ float red[256];
    float ex[2], ey[2];
    for (int cv = 0; cv < 2; ++cv){
      const float* A = aff + cv*6;
      ex[cv] = (A[0] + A[1])*128.0f + A[2];
      ey[cv] = (A[3] + A[4])*128.0f + A[5];
    }
    float dl = 0.0f;
    for (int p = 0; p < 4; ++p){
      int t = p*256 + tid;
      float cx = (float)((t & 31)*8 + 4), cy = (float)((t >> 5)*8 + 4);
      for (int cv = 0; cv < 2; ++cv){
        float dx = cx - ex[cv], dy = cy - ey[cv];
        dl = fmaxf(dl, sqrtf(dx*dx + dy*dy));
      }
    }
    red[tid] = dl; __syncthreads();
    for (int s = 128; s > 0; s >>= 1){
      if (tid < s) red[tid] = fmaxf(red[tid], red[tid + s]);
      __syncthreads();
    }
    float dmax = red[0] + 1e-6f;
    const float PI_F = 3.14159265358979f;
    for (int p = 0; p < 4; ++p){
      int t = p*256 + tid;
      float cx = (float)((t & 31)*8 + 4), cy = (float)((t >> 5)*8 + 4);
      for (int cv = 0; cv < 2; ++cv){
        float dx = cx - ex[cv], dy = cy - ey[cv];
        float d = sqrtf(dx*dx + dy*dy);
        float ang = atan2f(dy, dx);
        int db = (int)(d / dmax * 3.0f);
        int ab = (int)((ang + PI_F) / (2.0f*PI_F) * 3.0f);
        int idx = db*4 + ab;
        int bw = cv*1024 + t;
        for (int h2 = 0; h2 < 8; ++h2)
          egob[bw*8 + h2] = egot[idx*8 + h2];
      }
    }
  } else {                                // fused qkv bias (q part scaled)
    for (int j = tid; j < 768; j += 256)
      bqkv[j] = (j < 256) ? bq[j]*SCALE : bkv[j - 256];
  }
}

// ---------------------------------------------------------------------------
// Fused window attention: one block per window, 1024 threads (16 waves)
// ---------------------------------------------------------------------------
__global__ __launch_bounds__(1024) void attn_kernel(
    const float* __restrict__ x, const float* __restrict__ wvec,
    const float* __restrict__ bp, float* __restrict__ out,
    const unsigned short* __restrict__ wt, const float* __restrict__ relb,
    const float* __restrict__ egob, const float* __restrict__ bqkv)
{
  __shared__ unsigned short lds_x[NT*CDIM];      // 32 KiB: x(bf16) -> P scratch -> y(bf16)
  __shared__ unsigned short lds_qkv[NHEAD*6144]; // 96 KiB: per head {q 64x32, k 64x32, vT 32x64}

  const int b = blockIdx.x;
  const int tid = threadIdx.x;
  const int wv = tid >> 6, lane = tid & 63;
  const int quad = lane >> 4, cc = lane & 15;

  // ---- stage x window -> bf16 LDS (token-major, 256/row) ----
  const float4* xg = (const float4*)(x + (size_t)b*(NT*CDIM));
  for (int it = 0; it < 4; ++it){
    int i4 = tid + it*1024;
    float4 v = xg[i4];
    us4 pk = { f2bf(v.x), f2bf(v.y), f2bf(v.z), f2bf(v.w) };
    *(us4*)(&lds_x[i4*4]) = pk;
  }
  float w0 = wvec[0], w1 = wvec[1];
  float wm = fmaxf(w0, w1);
  float e0 = __expf(w0 - wm), e1 = __expf(w1 - wm);
  float ws0 = e0/(e0+e1), ws1 = e1/(e0+e1);
  __syncthreads();

  // ---- phase 1: qkv^T GEMM  (A = W^T rows from global/L2, B = x from LDS) ----
  {
    const int ob = wv*48;                 // 48 out_ch rows per wave (16 waves x 48 = 768)
    f4 acc[3][4];
    for (int mt=0;mt<3;++mt) for (int nt=0;nt<4;++nt) acc[mt][nt] = (f4){0,0,0,0};
    for (int ks = 0; ks < 8; ++ks){
      bfrag afr[3], bfr[4];
      for (int mt=0;mt<3;++mt)
        afr[mt] = *(const bfrag*)(wt + (ob + mt*16 + cc)*256 + ks*32 + quad*8);
      for (int nt=0;nt<4;++nt)
        bfr[nt] = *(const bfrag*)(&lds_x[(nt*16 + cc)*256 + ks*32 + quad*8]);
      for (int mt=0;mt<3;++mt)
        for (int nt=0;nt<4;++nt)
          acc[mt][nt] = mfma16(afr[mt], bfr[nt], acc[mt][nt]);
    }
    // C' frag: col = token = cc, rows = out_ch = oc0 + {0..3}
    for (int mt=0;mt<3;++mt){
      int oc0 = ob + mt*16 + quad*4;
      float bb0 = bqkv[oc0], bb1 = bqkv[oc0+1], bb2 = bqkv[oc0+2], bb3 = bqkv[oc0+3];
      int part = oc0 >> 8, ch = oc0 & 255;
      int h2 = ch >> 5, d0 = ch & 31;
      unsigned short* slab = &lds_qkv[h2*6144 + part*2048];
      for (int nt=0;nt<4;++nt){
        int tok = nt*16 + cc;
        float v0 = acc[mt][nt][0] + bb0;
        float v1 = acc[mt][nt][1] + bb1;
        float v2 = acc[mt][nt][2] + bb2;
        float v3 = acc[mt][nt][3] + bb3;
        if (part < 2){                    // q,k token-major: [tok][d]
          us4 pk = { f2bf(v0), f2bf(v1), f2bf(v2), f2bf(v3) };
          *(us4*)(&slab[tok*32 + d0]) = pk;
        } else {                          // v channel-major: vT[d][tok]
          slab[(d0+0)*64 + tok] = f2bf(v0);
          slab[(d0+1)*64 + tok] = f2bf(v1);
          slab[(d0+2)*64 + tok] = f2bf(v2);
          slab[(d0+3)*64 + tok] = f2bf(v3);
        }
      }
    }
  }
  __syncthreads();

  // ---- phase 2: attention. wave -> (head = wv>>1, row-half = wv&1) ----
  const int h = wv >> 1, half = wv & 1;
  f4 yacc[2][2];
  {
    const unsigned short* qs  = &lds_qkv[h*6144];
    const unsigned short* ks_ = qs + 2048;
    const unsigned short* vts = qs + 4096;
    float ego = egob[b*8 + h];
    const float* rb = relb + h*4096;

    bfrag bk[4];
    for (int jt=0;jt<4;++jt)
      bk[jt] = *(const bfrag*)(&ks_[(jt*16 + cc)*32 + quad*8]);
    f4 S[2][4];
    for (int it=0;it<2;++it){
      bfrag aq = *(const bfrag*)(&qs[(half*32 + it*16 + cc)*32 + quad*8]);
      for (int jt=0;jt<4;++jt){
        f4 z = (f4){0,0,0,0};
        S[it][jt] = mfma16(aq, bk[jt], z);   // K=32 = hd in one MFMA
      }
    }
    // logits + biases; S frag: col = j = jt*16+cc, row = i = quad*4+r
    float a[2][4][4];                        // [it][r][jt]
    for (int it=0;it<2;++it)
      for (int jt=0;jt<4;++jt){
        int jj = jt*16 + cc;
        for (int r=0;r<4;++r){
          int ii = half*32 + it*16 + quad*4 + r;
          a[it][r][jt] = S[it][jt][r] + rb[ii*64 + jj] + ego;
        }
      }
    // row stats (max, expsum) over 64 cols: 4 regs + 16 lanes (xor 1,2,4,8)
    float rmax[2][4], rinv[2][4];
    for (int it=0;it<2;++it)
      for (int r=0;r<4;++r){
        float m = fmaxf(fmaxf(a[it][r][0], a[it][r][1]), fmaxf(a[it][r][2], a[it][r][3]));
        for (int off=1; off<16; off<<=1) m = fmaxf(m, __shfl_xor(m, off, 64));
        float s = 0.0f;
        for (int jt=0;jt<4;++jt) s += __expf(a[it][r][jt] - m);
        for (int off=1; off<16; off<<=1) s += __shfl_xor(s, off, 64);
        rmax[it][r] = m; rinv[it][r] = 1.0f / s;
      }
    // blended P (C-layout) -> wave-private LDS chunk -> A-layout -> PV MFMA
    for (int it=0;it<2;++it) for (int nt=0;nt<2;++nt) yacc[it][nt] = (f4){0,0,0,0};
    unsigned short* Pw = &lds_x[wv*1024];    // 2 KiB per wave (32 rows x 32 cols)
    for (int chunk=0; chunk<2; ++chunk){
      for (int it=0;it<2;++it)
        for (int jtl=0;jtl<2;++jtl){
          int jt = chunk*2 + jtl;
          for (int r=0;r<4;++r){
            float av = a[it][r][jt];
            float rl = fmaxf(av, 0.0f);
            float p = ws0 * __expf(av - rmax[it][r]) * rinv[it][r] + ws1 * rl * rl;
            Pw[(it*16 + quad*4 + r)*32 + jtl*16 + cc] = f2bf(p);
          }
        }
      bfrag pa[2], pb[2];
      for (int itl=0;itl<2;++itl)
        pa[itl] = *(const bfrag*)(&Pw[(itl*16 + cc)*32 + quad*8]);
      for (int nt=0;nt<2;++nt)
        pb[nt] = *(const bfrag*)(&vts[(nt*16 + cc)*64 + chunk*32 + quad*8]);
      for (int itl=0;itl<2;++itl)
        for (int nt=0;nt<2;++nt)
          yacc[itl][nt] = mfma16(pa[itl], pb[nt], yacc[itl][nt]);
    }
  }
  __syncthreads();                           // all P reads done before y overwrites lds_x
  // y (64x256 bf16, token-major) into lds_x
  for (int itl=0;itl<2;++itl)
    for (int nt=0;nt<2;++nt)
      for (int r=0;r<4;++r){
        int ii = half*32 + itl*16 + quad*4 + r;
        lds_x[ii*256 + h*32 + nt*16 + cc] = f2bf(yacc[itl][nt][r]);
      }
  __syncthreads();

  // ---- phase 3: out = y @ Wp + bp ----
  {
    const int mt = wv & 3;                   // token tile
    const int cb = (wv >> 2)*64;             // 4 col tiles
    f4 o[4];
    for (int nt=0;nt<4;++nt) o[nt] = (f4){0,0,0,0};
    for (int ks=0; ks<8; ++ks){
      bfrag ay = *(const bfrag*)(&lds_x[(mt*16 + cc)*256 + ks*32 + quad*8]);
      for (int nt=0;nt<4;++nt){
        bfrag bw = *(const bfrag*)(wt + (768 + cb + nt*16 + cc)*256 + ks*32 + quad*8);
        o[nt] = mfma16(ay, bw, o[nt]);
      }
    }
    float* og = out + (size_t)b*(NT*CDIM);
    for (int nt=0;nt<4;++nt){
      int col = cb + nt*16 + cc;
      float bpv = bp[col];
      for (int r=0;r<4;++r){
        int tok = mt*16 + quad*4 + r;
        og[tok*256 + col] = o[nt][r] + bpv;
      }
    }
  }
}

extern "C" void kernel_launch(void* const* d_in, const int* in_sizes, int n_in,
                              void* d_out, int out_size, void* d_ws, size_t ws_size,
                              hipStream_t stream)
{
  const float* x    = (const float*)d_in[0];
  const float* aff  = (const float*)d_in[1];
  const float* Wq   = (const float*)d_in[2];
  const float* bq   = (const float*)d_in[3];
  const float* Wkv  = (const float*)d_in[4];
  const float* bkv  = (const float*)d_in[5];
  const float* Wp   = (const float*)d_in[6];
  const float* bp   = (const float*)d_in[7];
  const float* relt = (const float*)d_in[8];
  const float* egot = (const float*)d_in[9];
  const float* w    = (const float*)d_in[10];
  float* out = (float*)d_out;

  char* ws = (char*)d_ws;
  unsigned short* wt = (unsigned short*)ws;       // 512 KiB bf16 W^T
  float* relb = (float*)(ws + 524288);            // 128 KiB
  float* egob = (float*)(ws + 655360);            //  64 KiB
  float* bqkv = (float*)(ws + 720896);            //   3 KiB

  hipLaunchKernelGGL(prep_kernel, dim3(1154), dim3(256), 0, stream,
                     aff, Wq, bq, Wkv, bkv, Wp, relt, egot, wt, relb, egob, bqkv);
  hipLaunchKernelGGL(attn_kernel, dim3(2048), dim3(1024), 0, stream,
                     x, w, bp, out, wt, relb, egob, bqkv);
}